// Round 6
// baseline (240.445 us; speedup 1.0000x reference)
//
#include <hip/hip_runtime.h>
#include <hip/hip_bf16.h>

// Problem constants (B=4, S=2048, D=512, H=8, Dh=64)
#define BATCH 4
#define SEQ   2048
#define DIM   512
#define NH    8
#define DH    64
#define NTOK  (BATCH*SEQ)        // 8192

typedef __bf16 bf16x8 __attribute__((ext_vector_type(8)));
typedef __bf16 bf16x4 __attribute__((ext_vector_type(4)));
typedef float  f32x4  __attribute__((ext_vector_type(4)));

#define MFMA16(a,b,c) __builtin_amdgcn_mfma_f32_16x16x32_bf16((a),(b),(c),0,0,0)

#if __has_builtin(__builtin_amdgcn_exp2f)
#define EXP2F(x) __builtin_amdgcn_exp2f(x)
#else
#define EXP2F(x) exp2f(x)
#endif

// Q pre-scaled by log2(e)/8 in the projection epilogue -> softmax in exp2 space
#define QSCALE 0.18033688011112042f
// Fixed softmax shift (exp2 domain); see R4 notes. Makes partial attention
// results over disjoint k-ranges PURELY ADDITIVE (of += of', l += l').
#define SMAX 16.0f

// async global->LDS, 16 B per lane; LDS dest is wave-uniform base (+lane*16)
typedef __attribute__((address_space(1))) void GAS;
typedef __attribute__((address_space(3))) void LAS;
__device__ __forceinline__ void gl_lds16(const void* g, void* l) {
  __builtin_amdgcn_global_load_lds((GAS*)g, (LAS*)l, 16, 0, 0);
}

// ---------------------------------------------------------------------------
// fp32 -> bf16 convert, 8 elems/thread
// ---------------------------------------------------------------------------
__global__ __launch_bounds__(256) void cvt_f32_bf16(const float* __restrict__ src,
                                                    __bf16* __restrict__ dst, int n8) {
  int i = blockIdx.x * blockDim.x + threadIdx.x;
  if (i >= n8) return;
  const float4* s = (const float4*)src;
  float4 a = s[2*i], b = s[2*i+1];
  bf16x8 o;
  o[0] = (__bf16)a.x; o[1] = (__bf16)a.y; o[2] = (__bf16)a.z; o[3] = (__bf16)a.w;
  o[4] = (__bf16)b.x; o[5] = (__bf16)b.y; o[6] = (__bf16)b.z; o[7] = (__bf16)b.w;
  *(bf16x8*)&dst[8*i] = o;
}

__global__ __launch_bounds__(256) void cvt_weights(
    const float* __restrict__ s0, const float* __restrict__ s1,
    const float* __restrict__ s2, const float* __restrict__ s3,
    __bf16* __restrict__ o0, __bf16* __restrict__ o1,
    __bf16* __restrict__ o2, __bf16* __restrict__ o3) {
  int i = blockIdx.x * blockDim.x + threadIdx.x;   // 4 * 32768 chunks of 8
  const int which = i >> 15, off = i & 32767;
  const float* src = (which == 0) ? s0 : (which == 1) ? s1 : (which == 2) ? s2 : s3;
  __bf16* dst      = (which == 0) ? o0 : (which == 1) ? o1 : (which == 2) ? o2 : o3;
  const float4* s = (const float4*)src;
  float4 a = s[2*off], b = s[2*off+1];
  bf16x8 o;
  o[0] = (__bf16)a.x; o[1] = (__bf16)a.y; o[2] = (__bf16)a.z; o[3] = (__bf16)a.w;
  o[4] = (__bf16)b.x; o[5] = (__bf16)b.y; o[6] = (__bf16)b.z; o[7] = (__bf16)b.w;
  *(bf16x8*)&dst[8*off] = o;
}

// ---------------------------------------------------------------------------
// NT GEMM 128x128 tile, m97 structure: global_load_lds (16B) into linear
// LDS [128][64], 4 waves, 4x4 acc/wave.  z = 0/1/2 -> Q / K / V projection.
// Q written pre-scaled by log2e/8 (exp2-space softmax downstream).
// ---------------------------------------------------------------------------
__global__ __launch_bounds__(256) void gemm_qkv(
    const __bf16* __restrict__ xb,
    const __bf16* __restrict__ wq, const __bf16* __restrict__ wk,
    const __bf16* __restrict__ wv,
    const float* __restrict__ bq, const float* __restrict__ bk,
    const float* __restrict__ bv,
    __bf16* __restrict__ Qb, __bf16* __restrict__ Kb, __bf16* __restrict__ Vt)
{
  const int z = blockIdx.z;
  const __bf16* W    = (z == 0) ? wq : (z == 1) ? wk : wv;
  const float*  bias = (z == 0) ? bq : (z == 1) ? bk : bv;

  __shared__ __align__(16) __bf16 As[128*64];
  __shared__ __align__(16) __bf16 Bs[128*64];

  const int tid  = threadIdx.x;
  const int m0   = blockIdx.x * 128, n0 = blockIdx.y * 128;
  const int w    = tid >> 6, lane = tid & 63, quad = lane >> 4, l16 = lane & 15;
  const int wm   = (w >> 1) * 64, wn = (w & 1) * 64;
  const int srow = w*32 + (lane >> 3);
  const int scc  = (lane & 7) * 8;

  f32x4 acc[4][4] = {};

  for (int k0 = 0; k0 < DIM; k0 += 64) {
#pragma unroll
    for (int i = 0; i < 4; ++i) {
      const int row = srow + i*8;
      gl_lds16(&xb[(size_t)(m0+row)*DIM + k0 + scc], &As[(w*4+i)*512]);
      gl_lds16(&W [(size_t)(n0+row)*DIM + k0 + scc], &Bs[(w*4+i)*512]);
    }
    __syncthreads();
#pragma unroll
    for (int kk = 0; kk < 2; ++kk) {
      const int ko = kk*32 + quad*8;
      bf16x8 af[4], bfr[4];
#pragma unroll
      for (int f = 0; f < 4; ++f) {
        af[f]  = *(const bf16x8*)&As[(wm + f*16 + l16)*64 + ko];
        bfr[f] = *(const bf16x8*)&Bs[(wn + f*16 + l16)*64 + ko];
      }
#pragma unroll
      for (int fm = 0; fm < 4; ++fm)
#pragma unroll
        for (int fn = 0; fn < 4; ++fn)
          acc[fm][fn] = MFMA16(af[fm], bfr[fn], acc[fm][fn]);
    }
    __syncthreads();
  }

  // epilogue: C row = m0+wm+fm*16+quad*4+r ; col = n0+wn+fn*16+l16
#pragma unroll
  for (int fm = 0; fm < 4; ++fm) {
#pragma unroll
    for (int fn = 0; fn < 4; ++fn) {
      const int col  = n0 + wn + fn*16 + l16;
      const float bc = bias[col];
      const int h = col >> 6, dh = col & 63;
#pragma unroll
      for (int r = 0; r < 4; ++r) {
        const int row = m0 + wm + fm*16 + quad*4 + r;
        const int b = row >> 11, s = row & 2047;
        const float v = acc[fm][fn][r] + bc;
        if (z == 2) {
          Vt[((size_t)(b*NH + h)*DH + dh)*SEQ + s] = (__bf16)v;
        } else if (z == 0) {
          Qb[((size_t)(b*NH + h)*SEQ + s)*DH + dh] = (__bf16)(v * QSCALE);
        } else {
          Kb[((size_t)(b*NH + h)*SEQ + s)*DH + dh] = (__bf16)v;
        }
      }
    }
  }
}

// ---------------------------------------------------------------------------
// Output projection (same m97-style staging), fp32 out
// ---------------------------------------------------------------------------
__global__ __launch_bounds__(256) void gemm_out(
    const __bf16* __restrict__ attnb, const __bf16* __restrict__ wo,
    const float* __restrict__ bo, float* __restrict__ out)
{
  __shared__ __align__(16) __bf16 As[128*64];
  __shared__ __align__(16) __bf16 Bs[128*64];

  const int tid = threadIdx.x;
  const int m0  = blockIdx.x * 128, n0 = blockIdx.y * 128;
  const int w   = tid >> 6, lane = tid & 63, quad = lane >> 4, l16 = lane & 15;
  const int wm  = (w >> 1) * 64, wn = (w & 1) * 64;
  const int srow = w*32 + (lane >> 3);
  const int scc  = (lane & 7) * 8;

  f32x4 acc[4][4] = {};

  for (int k0 = 0; k0 < DIM; k0 += 64) {
#pragma unroll
    for (int i = 0; i < 4; ++i) {
      const int row = srow + i*8;
      gl_lds16(&attnb[(size_t)(m0+row)*DIM + k0 + scc], &As[(w*4+i)*512]);
      gl_lds16(&wo   [(size_t)(n0+row)*DIM + k0 + scc], &Bs[(w*4+i)*512]);
    }
    __syncthreads();
#pragma unroll
    for (int kk = 0; kk < 2; ++kk) {
      const int ko = kk*32 + quad*8;
      bf16x8 af[4], bfr[4];
#pragma unroll
      for (int f = 0; f < 4; ++f) {
        af[f]  = *(const bf16x8*)&As[(wm + f*16 + l16)*64 + ko];
        bfr[f] = *(const bf16x8*)&Bs[(wn + f*16 + l16)*64 + ko];
      }
#pragma unroll
      for (int fm = 0; fm < 4; ++fm)
#pragma unroll
        for (int fn = 0; fn < 4; ++fn)
          acc[fm][fn] = MFMA16(af[fm], bfr[fn], acc[fm][fn]);
    }
    __syncthreads();
  }

#pragma unroll
  for (int fm = 0; fm < 4; ++fm) {
#pragma unroll
    for (int fn = 0; fn < 4; ++fn) {
      const int col  = n0 + wn + fn*16 + l16;
      const float bc = bo[col];
#pragma unroll
      for (int r = 0; r < 4; ++r) {
        const int row = m0 + wm + fm*16 + quad*4 + r;
        out[(size_t)row*DIM + col] = acc[fm][fn][r] + bc;
      }
    }
  }
}

// ---------------------------------------------------------------------------
// Flash attention v8 = v7 per-step machinery (fixed-max exp2 softmax, K reg
// ping-pong, V early, setprio, per-lane l) with ADDITIVE SPLIT-K items:
//   idx in [0,2048):  q-tiles t=32..63 split into 2 contiguous k-chunks
//                     (8..16 tiles each); partials atomicAdd'ed into f32
//                     Of/Lb buffers (fixed-max => merge is pure addition).
//   idx in [2048,3072): q-tiles t=0..31 whole (1..16 tiles), direct bf16 out.
// Max serial item drops 32 -> 16 steps; 3072 equal-capacity waves.
// ---------------------------------------------------------------------------
__global__ __launch_bounds__(64) void flash_attn(
    const __bf16* __restrict__ Qb, const __bf16* __restrict__ Kb,
    const __bf16* __restrict__ Vt, __bf16* __restrict__ attnb,
    float* __restrict__ Of, float* __restrict__ Lb)
{
  const int idx = blockIdx.x;
  const int bh  = idx & 31;                    // same-bh blocks share an XCD L2
  const int b   = bh >> 3, h = bh & 7;
  const int lane = threadIdx.x & 63, quad = lane >> 4, l16 = lane & 15;

  int t, c0tile, c1tile;
  bool split;
  if (idx < 2048) {                            // heavy halves, dispatched first
    t = 63 - (idx >> 6);                       // 63..32
    const int ktiles = (t >> 1) + 1;           // 32..17
    const int half   = ktiles >> 1;
    const int c      = (idx >> 5) & 1;
    c0tile = c ? half : 0;
    c1tile = c ? ktiles : half;
    split  = true;
  } else {
    const int li = idx - 2048;
    t = 31 - (li >> 5);                        // 31..0
    c0tile = 0;
    c1tile = (t >> 1) + 1;                     // 16..1
    split  = false;
  }
  const int q0 = t * 32;

  const __bf16* Qp = Qb + (size_t)bh * SEQ * DH;   // [s][dh], pre-scaled
  const __bf16* Kp = Kb + (size_t)bh * SEQ * DH;   // [s][dh]
  const __bf16* Vp = Vt + (size_t)bh * DH * SEQ;   // [dh][s]

  __shared__ __align__(16) __bf16 Pw[32*88];       // P transpose patch, stride 88

  // Q fragments (already scaled by log2e/8 at projection)
  bf16x8 qf[2][2];
#pragma unroll
  for (int mf = 0; mf < 2; ++mf)
#pragma unroll
    for (int kk = 0; kk < 2; ++kk)
      qf[mf][kk] = *(const bf16x8*)&Qp[(size_t)(q0 + mf*16 + l16)*DH + kk*32 + quad*8];

  f32x4 of[2][4] = {};
  float l_[2][4];                              // PER-LANE partial sums
#pragma unroll
  for (int mf = 0; mf < 2; ++mf)
#pragma unroll
    for (int r = 0; r < 4; ++r) l_[mf][r] = 0.f;

  bf16x8 kfA[4][2], kfB[4][2];
  // prologue: first K tile of this item's range
#pragma unroll
  for (int fn = 0; fn < 4; ++fn)
#pragma unroll
    for (int kk = 0; kk < 2; ++kk)
      kfA[fn][kk] = *(const bf16x8*)&Kp[(size_t)(c0tile*64 + fn*16 + l16)*DH + kk*32 + quad*8];

#define TILE_STEP(KC, KN, KT)                                                  \
  {                                                                            \
    const int k0 = (KT) * 64;                                                  \
    /* V for this tile — issued first, consumed after softmax */               \
    bf16x8 vf[4][2];                                                           \
    _Pragma("unroll")                                                          \
    for (int nd = 0; nd < 4; ++nd)                                             \
      _Pragma("unroll")                                                        \
      for (int kq = 0; kq < 2; ++kq)                                           \
        vf[nd][kq] = *(const bf16x8*)&Vp[(size_t)(nd*16 + l16)*SEQ + k0 +      \
                                         kq*32 + quad*8];                      \
    /* prefetch next K tile into the other buffer */                           \
    {                                                                          \
      const int kn0 = ((KT) + 1 < c1tile) ? k0 + 64 : 0;                       \
      _Pragma("unroll")                                                        \
      for (int fn = 0; fn < 4; ++fn)                                           \
        _Pragma("unroll")                                                      \
        for (int kk = 0; kk < 2; ++kk)                                         \
          KN[fn][kk] = *(const bf16x8*)&Kp[(size_t)(kn0 + fn*16 + l16)*DH +    \
                                           kk*32 + quad*8];                    \
    }                                                                          \
    /* QK^T (16 MFMAs), scores in log2 domain */                               \
    f32x4 sf[2][4] = {};                                                       \
    __builtin_amdgcn_s_setprio(1);                                             \
    _Pragma("unroll")                                                          \
    for (int mf = 0; mf < 2; ++mf)                                             \
      _Pragma("unroll")                                                        \
      for (int fn = 0; fn < 4; ++fn) {                                         \
        sf[mf][fn] = MFMA16(qf[mf][0], KC[fn][0], sf[mf][fn]);                 \
        sf[mf][fn] = MFMA16(qf[mf][1], KC[fn][1], sf[mf][fn]);                 \
      }                                                                        \
    __builtin_amdgcn_s_setprio(0);                                             \
    /* causal mask (only diagonal-crossing tiles) */                           \
    if (k0 + 63 > q0) {                                                        \
      _Pragma("unroll")                                                        \
      for (int mf = 0; mf < 2; ++mf)                                           \
        _Pragma("unroll")                                                      \
        for (int fn = 0; fn < 4; ++fn) {                                       \
          const int col = k0 + fn*16 + l16;                                    \
          _Pragma("unroll")                                                    \
          for (int r = 0; r < 4; ++r) {                                        \
            const int row = q0 + mf*16 + quad*4 + r;                           \
            if (col > row) sf[mf][fn][r] = -1e30f;                             \
          }                                                                    \
        }                                                                      \
    }                                                                          \
    /* fixed-max exp2: P = exp2(sf - SMAX); masked -> 0 */                     \
    _Pragma("unroll")                                                          \
    for (int mf = 0; mf < 2; ++mf)                                             \
      _Pragma("unroll")                                                        \
      for (int fn = 0; fn < 4; ++fn)                                           \
        _Pragma("unroll")                                                      \
        for (int r = 0; r < 4; ++r)                                            \
          sf[mf][fn][r] = EXP2F(sf[mf][fn][r] - SMAX);                         \
    _Pragma("unroll")                                                          \
    for (int mf = 0; mf < 2; ++mf)                                             \
      _Pragma("unroll")                                                        \
      for (int r = 0; r < 4; ++r)                                              \
        l_[mf][r] += (sf[mf][0][r] + sf[mf][1][r]) +                           \
                     (sf[mf][2][r] + sf[mf][3][r]);                            \
    /* P: C-layout -> LDS -> A-layout */                                       \
    _Pragma("unroll")                                                          \
    for (int mf = 0; mf < 2; ++mf)                                             \
      _Pragma("unroll")                                                        \
      for (int fn = 0; fn < 4; ++fn)                                           \
        _Pragma("unroll")                                                      \
        for (int r = 0; r < 4; ++r)                                            \
          Pw[(mf*16 + quad*4 + r)*88 + fn*16 + l16] = (__bf16)sf[mf][fn][r];   \
    bf16x8 pa[2][2];                                                           \
    _Pragma("unroll")                                                          \
    for (int mf = 0; mf < 2; ++mf)                                             \
      _Pragma("unroll")                                                        \
      for (int kq = 0; kq < 2; ++kq)                                           \
        pa[mf][kq] = *(const bf16x8*)&Pw[(mf*16 + l16)*88 + kq*32 + quad*8];   \
    /* O += P V (16 MFMAs) */                                                  \
    __builtin_amdgcn_s_setprio(1);                                             \
    _Pragma("unroll")                                                          \
    for (int mf = 0; mf < 2; ++mf)                                             \
      _Pragma("unroll")                                                        \
      for (int nd = 0; nd < 4; ++nd) {                                         \
        of[mf][nd] = MFMA16(pa[mf][0], vf[nd][0], of[mf][nd]);                 \
        of[mf][nd] = MFMA16(pa[mf][1], vf[nd][1], of[mf][nd]);                 \
      }                                                                        \
    __builtin_amdgcn_s_setprio(0);                                             \
  }

  for (int kt = c0tile; kt < c1tile; kt += 2) {
    TILE_STEP(kfA, kfB, kt);
    if (kt + 1 < c1tile) TILE_STEP(kfB, kfA, kt + 1);
  }
#undef TILE_STEP

  // ---- deferred l reduction (once per item) ----
#pragma unroll
  for (int d = 1; d < 16; d <<= 1)
#pragma unroll
    for (int mf = 0; mf < 2; ++mf)
#pragma unroll
      for (int r = 0; r < 4; ++r)
        l_[mf][r] += __shfl_xor(l_[mf][r], d);

  if (!split) {
    // whole q-tile: normalize + store merged-head layout [B, S, H*Dh]
#pragma unroll
    for (int mf = 0; mf < 2; ++mf)
#pragma unroll
      for (int r = 0; r < 4; ++r)
        l_[mf][r] = 1.0f / l_[mf][r];
#pragma unroll
    for (int mf = 0; mf < 2; ++mf)
#pragma unroll
      for (int nd = 0; nd < 4; ++nd) {
        const int dh = nd*16 + l16;
#pragma unroll
        for (int r = 0; r < 4; ++r) {
          const int q = q0 + mf*16 + quad*4 + r;
          attnb[((size_t)b*SEQ + q)*DIM + h*DH + dh] = (__bf16)(of[mf][nd][r] * l_[mf][r]);
        }
      }
  } else {
    // k-chunk: additive merge into f32 partial buffers (rows q0-1024..+31)
    const int ro = (bh << 10) + (q0 - 1024);
    if (l16 == 0) {
#pragma unroll
      for (int mf = 0; mf < 2; ++mf)
#pragma unroll
        for (int r = 0; r < 4; ++r)
          atomicAdd(&Lb[ro + mf*16 + quad*4 + r], l_[mf][r]);
    }
#pragma unroll
    for (int mf = 0; mf < 2; ++mf)
#pragma unroll
      for (int nd = 0; nd < 4; ++nd) {
        const int dh = nd*16 + l16;
#pragma unroll
        for (int r = 0; r < 4; ++r)
          atomicAdd(&Of[(size_t)(ro + mf*16 + quad*4 + r)*DH + dh], of[mf][nd][r]);
      }
  }
}

// ---------------------------------------------------------------------------
// Normalize split rows (q in [1024,2048) per (b,h)): attnb = Of / L, bf16.
// 524288 threads x 4 dh elems.
// ---------------------------------------------------------------------------
__global__ __launch_bounds__(256) void norm_split(
    const float* __restrict__ Of, const float* __restrict__ Lb,
    __bf16* __restrict__ attnb)
{
  const int i = blockIdx.x * 256 + threadIdx.x;
  const int e = i * 4;
  const int bh  = e >> 16;            // 1024*64 f32 per bh
  const int rem = e & 65535;
  const int row = rem >> 6;
  const int dh  = rem & 63;
  const f32x4 v = *(const f32x4*)&Of[e];
  const float inv = 1.0f / Lb[(bh << 10) + row];
  bf16x4 o;
  o[0] = (__bf16)(v[0] * inv); o[1] = (__bf16)(v[1] * inv);
  o[2] = (__bf16)(v[2] * inv); o[3] = (__bf16)(v[3] * inv);
  const int b = bh >> 3, h = bh & 7, q = 1024 + row;
  *(bf16x4*)&attnb[((size_t)b*SEQ + q)*DIM + h*DH + dh] = o;
}

// ---------------------------------------------------------------------------
extern "C" void kernel_launch(void* const* d_in, const int* in_sizes, int n_in,
                              void* d_out, int out_size, void* d_ws, size_t ws_size,
                              hipStream_t stream) {
  const float* x  = (const float*)d_in[0];
  // d_in[1] = causal mask, unused (causality computed analytically)
  const float* Wq = (const float*)d_in[2];
  const float* bq = (const float*)d_in[3];
  const float* Wk = (const float*)d_in[4];
  const float* bk = (const float*)d_in[5];
  const float* Wv = (const float*)d_in[6];
  const float* bv = (const float*)d_in[7];
  const float* Wo = (const float*)d_in[8];
  const float* bo = (const float*)d_in[9];
  float* out = (float*)d_out;

  // workspace carve-up (bf16 elements), total ~44 MB
  __bf16* xb    = (__bf16*)d_ws;
  __bf16* wq    = xb + (size_t)NTOK*DIM;
  __bf16* wk    = wq + DIM*DIM;
  __bf16* wv    = wk + DIM*DIM;
  __bf16* wo    = wv + DIM*DIM;
  __bf16* Qb    = wo + DIM*DIM;
  __bf16* Kb    = Qb + (size_t)NTOK*DIM;
  __bf16* Vt    = Kb + (size_t)NTOK*DIM;
  __bf16* attnb = Vt + (size_t)NTOK*DIM;

  // f32 partial buffers ALIASED onto regions dead after gemm_qkv:
  //   Of: 32*1024*64 f32 = 8.39 MB  == xb region exactly
  //   Lb: 32*1024    f32 = 131 KB   <= wq region (512 KB)
  float* Of = (float*)xb;
  float* Lb = (float*)wq;

  // converts (2 launches)
  cvt_f32_bf16<<<(NTOK*DIM/8)/256, 256, 0, stream>>>(x, xb, NTOK*DIM/8);
  cvt_weights<<<(4*DIM*DIM/8)/256, 256, 0, stream>>>(Wq, Wk, Wv, Wo, wq, wk, wv, wo);

  // Q/K/V projections (consumes xb, wq..wv)
  gemm_qkv<<<dim3(NTOK/128, DIM/128, 3), 256, 0, stream>>>(
      xb, wq, wk, wv, bq, bk, bv, Qb, Kb, Vt);

  // zero partial buffers (xb/wq now dead)
  hipMemsetAsync(Of, 0, (size_t)32*1024*64*sizeof(float), stream);
  hipMemsetAsync(Lb, 0, (size_t)32*1024*sizeof(float), stream);

  // flash attention: 2048 split-chunk items (heavy-first) + 1024 whole items
  flash_attn<<<3072, 64, 0, stream>>>(Qb, Kb, Vt, attnb, Of, Lb);

  // normalize split rows into attnb
  norm_split<<<2048, 256, 0, stream>>>(Of, Lb, attnb);

  // output projection
  gemm_out<<<dim3(NTOK/128, DIM/128), 256, 0, stream>>>(attnb, wo, bo, out);
}

// Round 8
// 200.203 us; speedup vs baseline: 1.2010x; 1.2010x over previous
//
#include <hip/hip_runtime.h>
#include <hip/hip_bf16.h>

// Problem constants (B=4, S=2048, D=512, H=8, Dh=64)
#define BATCH 4
#define SEQ   2048
#define DIM   512
#define NH    8
#define DH    64
#define NTOK  (BATCH*SEQ)        // 8192

typedef __bf16 bf16x8 __attribute__((ext_vector_type(8)));
typedef float  f32x4  __attribute__((ext_vector_type(4)));

#define MFMA16(a,b,c) __builtin_amdgcn_mfma_f32_16x16x32_bf16((a),(b),(c),0,0,0)

#if __has_builtin(__builtin_amdgcn_exp2f)
#define EXP2F(x) __builtin_amdgcn_exp2f(x)
#else
#define EXP2F(x) exp2f(x)
#endif

// Q pre-scaled by log2(e)/8 in the projection epilogue -> softmax in exp2 space
#define QSCALE 0.18033688011112042f
// Fixed softmax shift (exp2 domain): scores ~N(0,1), 6-sigma tail -> sf<=~10
// < 16, so P=exp2(sf-16) in [2^-42,2^-6] — no overflow/underflow; softmax is
// exactly invariant to the shift after l-normalization. Masked: exp2(-1e30)=0.
#define SMAX 16.0f

// async global->LDS, 16 B per lane; LDS dest is wave-uniform base (+lane*16)
typedef __attribute__((address_space(1))) void GAS;
typedef __attribute__((address_space(3))) void LAS;
__device__ __forceinline__ void gl_lds16(const void* g, void* l) {
  __builtin_amdgcn_global_load_lds((GAS*)g, (LAS*)l, 16, 0, 0);
}

// ---------------------------------------------------------------------------
// All fp32 -> bf16 converts in ONE launch: x (524288 chunks) + 4 weights
// (131072 chunks). Each chunk = 8 elems.
// ---------------------------------------------------------------------------
__global__ __launch_bounds__(256) void cvt_all(
    const float* __restrict__ x,
    const float* __restrict__ s0, const float* __restrict__ s1,
    const float* __restrict__ s2, const float* __restrict__ s3,
    __bf16* __restrict__ xb,
    __bf16* __restrict__ o0, __bf16* __restrict__ o1,
    __bf16* __restrict__ o2, __bf16* __restrict__ o3) {
  const int i = blockIdx.x * 256 + threadIdx.x;
  const float* src;
  __bf16* dst;
  int off;
  if (i < 524288) {                // x: NTOK*DIM/8 chunks
    src = x; dst = xb; off = i;
  } else {
    const int j = i - 524288;      // weights: 4 * 32768 chunks
    const int which = j >> 15; off = j & 32767;
    src = (which == 0) ? s0 : (which == 1) ? s1 : (which == 2) ? s2 : s3;
    dst = (which == 0) ? o0 : (which == 1) ? o1 : (which == 2) ? o2 : o3;
  }
  const float4* s = (const float4*)src;
  float4 a = s[2*off], b = s[2*off+1];
  bf16x8 o;
  o[0] = (__bf16)a.x; o[1] = (__bf16)a.y; o[2] = (__bf16)a.z; o[3] = (__bf16)a.w;
  o[4] = (__bf16)b.x; o[5] = (__bf16)b.y; o[6] = (__bf16)b.z; o[7] = (__bf16)b.w;
  *(bf16x8*)&dst[8*off] = o;
}

// ---------------------------------------------------------------------------
// NT GEMM 128x128 tile, m97 structure: global_load_lds (16B) into linear
// LDS [128][64], 4 waves, 4x4 acc/wave.  z = 0/1/2 -> Q / K / V projection.
// Epilogue re-tiles C through LDS (stride 152) so ALL global stores are
// coalesced 16B dwordx4 (Q/K: 128B contiguous per (row,head); V^T: 128B
// contiguous per dh-row) instead of 64 scattered 2B stores per thread.
// ---------------------------------------------------------------------------
__global__ __launch_bounds__(256) void gemm_qkv(
    const __bf16* __restrict__ xb,
    const __bf16* __restrict__ wq, const __bf16* __restrict__ wk,
    const __bf16* __restrict__ wv,
    const float* __restrict__ bq, const float* __restrict__ bk,
    const float* __restrict__ bv,
    __bf16* __restrict__ Qb, __bf16* __restrict__ Kb, __bf16* __restrict__ Vt)
{
  const int z = blockIdx.z;
  const __bf16* W    = (z == 0) ? wq : (z == 1) ? wk : wv;
  const float*  bias = (z == 0) ? bq : (z == 1) ? bk : bv;

  // one buffer: loop uses [0,32KB) as As|Bs; epilogue reuses all as Cs[128][152]
  __shared__ __align__(16) __bf16 smem[128*152];
  __bf16* As = smem;               // 128*64
  __bf16* Bs = smem + 128*64;      // 128*64

  const int tid  = threadIdx.x;
  const int m0   = blockIdx.x * 128, n0 = blockIdx.y * 128;
  const int w    = tid >> 6, lane = tid & 63, quad = lane >> 4, l16 = lane & 15;
  const int wm   = (w >> 1) * 64, wn = (w & 1) * 64;
  const int srow = w*32 + (lane >> 3);
  const int scc  = (lane & 7) * 8;

  f32x4 acc[4][4] = {};

  for (int k0 = 0; k0 < DIM; k0 += 64) {
#pragma unroll
    for (int i = 0; i < 4; ++i) {
      const int row = srow + i*8;
      gl_lds16(&xb[(size_t)(m0+row)*DIM + k0 + scc], &As[(w*4+i)*512]);
      gl_lds16(&W [(size_t)(n0+row)*DIM + k0 + scc], &Bs[(w*4+i)*512]);
    }
    __syncthreads();
#pragma unroll
    for (int kk = 0; kk < 2; ++kk) {
      const int ko = kk*32 + quad*8;
      bf16x8 af[4], bfr[4];
#pragma unroll
      for (int f = 0; f < 4; ++f) {
        af[f]  = *(const bf16x8*)&As[(wm + f*16 + l16)*64 + ko];
        bfr[f] = *(const bf16x8*)&Bs[(wn + f*16 + l16)*64 + ko];
      }
#pragma unroll
      for (int fm = 0; fm < 4; ++fm)
#pragma unroll
        for (int fn = 0; fn < 4; ++fn)
          acc[fm][fn] = MFMA16(af[fm], bfr[fn], acc[fm][fn]);
    }
    __syncthreads();
  }

  // ---- epilogue: C -> LDS (bf16, +bias, Q pre-scale) -> coalesced stores ----
  __bf16* Cs = smem;               // stride 152
#pragma unroll
  for (int fm = 0; fm < 4; ++fm) {
#pragma unroll
    for (int fn = 0; fn < 4; ++fn) {
      const int cl  = wn + fn*16 + l16;          // local col
      const float bc = bias[n0 + cl];
#pragma unroll
      for (int r = 0; r < 4; ++r) {
        const int rl = wm + fm*16 + quad*4 + r;  // local row
        float v = acc[fm][fn][r] + bc;
        if (z == 0) v *= QSCALE;
        Cs[rl*152 + cl] = (__bf16)v;
      }
    }
  }
  __syncthreads();

  if (z < 2) {
    // Q/K layout [bh][s][dh]: (row, head-half) -> 64 dh contiguous = 128B
    const int r  = tid >> 1, hh = tid & 1;
    const int grow = m0 + r, b = grow >> 11, s = grow & 2047;
    const int h  = (n0 >> 6) + hh;
    __bf16* O = (z == 0) ? Qb : Kb;
    __bf16* dst = O + ((size_t)(b*NH + h)*SEQ + s)*DH;
    const __bf16* srcr = &Cs[r*152 + hh*64];
#pragma unroll
    for (int j = 0; j < 8; ++j)
      *(bf16x8*)&dst[j*8] = *(const bf16x8*)&srcr[j*8];
  } else {
    // V^T layout [bh][dh][s]: (col, row-half) -> 64 s contiguous = 128B
    const int c  = tid >> 1, hh = tid & 1;
    const int col = n0 + c, h = col >> 6, dh = col & 63;
    const int b  = m0 >> 11, sbase = (m0 & 2047) + hh*64;
    __bf16* dst = Vt + ((size_t)(b*NH + h)*DH + dh)*SEQ + sbase;
#pragma unroll
    for (int j8 = 0; j8 < 8; ++j8) {
      bf16x8 o;
#pragma unroll
      for (int e = 0; e < 8; ++e)
        o[e] = Cs[(hh*64 + j8*8 + e)*152 + c];
      *(bf16x8*)&dst[j8*8] = o;
    }
  }
}

// ---------------------------------------------------------------------------
// Output projection, 64x128 tile -> 512 blocks (2 blocks/CU: barrier drains
// overlap across blocks). 4 waves, 2x4 acc/wave. fp32 out.
// ---------------------------------------------------------------------------
__global__ __launch_bounds__(256) void gemm_out(
    const __bf16* __restrict__ attnb, const __bf16* __restrict__ wo,
    const float* __restrict__ bo, float* __restrict__ out)
{
  __shared__ __align__(16) __bf16 As[64*64];
  __shared__ __align__(16) __bf16 Bs[128*64];

  const int tid = threadIdx.x;
  const int m0  = blockIdx.x * 64, n0 = blockIdx.y * 128;
  const int w   = tid >> 6, lane = tid & 63, quad = lane >> 4, l16 = lane & 15;
  const int wm  = (w >> 1) * 32, wn = (w & 1) * 64;
  const int srow = w*8 + (lane >> 3);      // A/B staging row base
  const int scc  = (lane & 7) * 8;

  f32x4 acc[2][4] = {};

  for (int k0 = 0; k0 < DIM; k0 += 64) {
#pragma unroll
    for (int i = 0; i < 2; ++i)            // A: 64x64 = 512 chunks
      gl_lds16(&attnb[(size_t)(m0 + srow + i*32)*DIM + k0 + scc],
               &As[(i*4 + w)*512]);
#pragma unroll
    for (int i = 0; i < 4; ++i)            // B: 128x64 = 1024 chunks
      gl_lds16(&wo[(size_t)(n0 + srow + i*32)*DIM + k0 + scc],
               &Bs[(i*4 + w)*512]);
    __syncthreads();
#pragma unroll
    for (int kk = 0; kk < 2; ++kk) {
      const int ko = kk*32 + quad*8;
      bf16x8 af[2], bfr[4];
#pragma unroll
      for (int f = 0; f < 2; ++f)
        af[f]  = *(const bf16x8*)&As[(wm + f*16 + l16)*64 + ko];
#pragma unroll
      for (int f = 0; f < 4; ++f)
        bfr[f] = *(const bf16x8*)&Bs[(wn + f*16 + l16)*64 + ko];
#pragma unroll
      for (int fm = 0; fm < 2; ++fm)
#pragma unroll
        for (int fn = 0; fn < 4; ++fn)
          acc[fm][fn] = MFMA16(af[fm], bfr[fn], acc[fm][fn]);
    }
    __syncthreads();
  }

#pragma unroll
  for (int fm = 0; fm < 2; ++fm) {
#pragma unroll
    for (int fn = 0; fn < 4; ++fn) {
      const int col  = n0 + wn + fn*16 + l16;
      const float bc = bo[col];
#pragma unroll
      for (int r = 0; r < 4; ++r) {
        const int row = m0 + wm + fm*16 + quad*4 + r;
        out[(size_t)row*DIM + col] = acc[fm][fn][r] + bc;
      }
    }
  }
}

// ---------------------------------------------------------------------------
// Flash attention v7 (known-good 70.1 us): 2048 one-wave blocks,
// 32 q-rows, 64-key tiles, K reg ping-pong, V issued early, setprio,
// fixed-max exp2 softmax (no online max / rescale), deferred per-lane l.
// ---------------------------------------------------------------------------
__global__ __launch_bounds__(64) void flash_attn(
    const __bf16* __restrict__ Qb, const __bf16* __restrict__ Kb,
    const __bf16* __restrict__ Vt, __bf16* __restrict__ attnb)
{
  const int idx = blockIdx.x;
  const int bh  = idx & 31;                    // same-bh blocks share an XCD L2
  const int t   = 63 - (idx >> 5);             // heavy q-tiles dispatch first
  const int b   = bh >> 3, h = bh & 7;
  const int lane = threadIdx.x & 63, quad = lane >> 4, l16 = lane & 15;
  const int q0  = t * 32;

  const __bf16* Qp = Qb + (size_t)bh * SEQ * DH;   // [s][dh], pre-scaled
  const __bf16* Kp = Kb + (size_t)bh * SEQ * DH;   // [s][dh]
  const __bf16* Vp = Vt + (size_t)bh * DH * SEQ;   // [dh][s]

  __shared__ __align__(16) __bf16 Pw[32*88];       // P transpose patch, stride 88

  // Q fragments (already scaled by log2e/8 at projection)
  bf16x8 qf[2][2];
#pragma unroll
  for (int mf = 0; mf < 2; ++mf)
#pragma unroll
    for (int kk = 0; kk < 2; ++kk)
      qf[mf][kk] = *(const bf16x8*)&Qp[(size_t)(q0 + mf*16 + l16)*DH + kk*32 + quad*8];

  f32x4 of[2][4] = {};
  float l_[2][4];                              // PER-LANE partial sums
#pragma unroll
  for (int mf = 0; mf < 2; ++mf)
#pragma unroll
    for (int r = 0; r < 4; ++r) l_[mf][r] = 0.f;

  const int ktiles = (q0 >> 6) + 1;            // covers keys [0, q0+32)

  bf16x8 kfA[4][2], kfB[4][2];
  // prologue: K tile 0 into buffer A
#pragma unroll
  for (int fn = 0; fn < 4; ++fn)
#pragma unroll
    for (int kk = 0; kk < 2; ++kk)
      kfA[fn][kk] = *(const bf16x8*)&Kp[(size_t)(fn*16 + l16)*DH + kk*32 + quad*8];

#define TILE_STEP(KC, KN, KT)                                                  \
  {                                                                            \
    const int k0 = (KT) * 64;                                                  \
    /* V for this tile — issued first, consumed after softmax */               \
    bf16x8 vf[4][2];                                                           \
    _Pragma("unroll")                                                          \
    for (int nd = 0; nd < 4; ++nd)                                             \
      _Pragma("unroll")                                                        \
      for (int kq = 0; kq < 2; ++kq)                                           \
        vf[nd][kq] = *(const bf16x8*)&Vp[(size_t)(nd*16 + l16)*SEQ + k0 +      \
                                         kq*32 + quad*8];                      \
    /* prefetch next K tile into the other buffer */                           \
    {                                                                          \
      const int kn0 = ((KT) + 1 < ktiles) ? k0 + 64 : 0;                       \
      _Pragma("unroll")                                                        \
      for (int fn = 0; fn < 4; ++fn)                                           \
        _Pragma("unroll")                                                      \
        for (int kk = 0; kk < 2; ++kk)                                         \
          KN[fn][kk] = *(const bf16x8*)&Kp[(size_t)(kn0 + fn*16 + l16)*DH +    \
                                           kk*32 + quad*8];                    \
    }                                                                          \
    /* QK^T (16 MFMAs), scores in log2 domain */                               \
    f32x4 sf[2][4] = {};                                                       \
    __builtin_amdgcn_s_setprio(1);                                             \
    _Pragma("unroll")                                                          \
    for (int mf = 0; mf < 2; ++mf)                                             \
      _Pragma("unroll")                                                        \
      for (int fn = 0; fn < 4; ++fn) {                                         \
        sf[mf][fn] = MFMA16(qf[mf][0], KC[fn][0], sf[mf][fn]);                 \
        sf[mf][fn] = MFMA16(qf[mf][1], KC[fn][1], sf[mf][fn]);                 \
      }                                                                        \
    __builtin_amdgcn_s_setprio(0);                                             \
    /* causal mask (only diagonal-crossing tiles) */                           \
    if (k0 + 63 > q0) {                                                        \
      _Pragma("unroll")                                                        \
      for (int mf = 0; mf < 2; ++mf)                                           \
        _Pragma("unroll")                                                      \
        for (int fn = 0; fn < 4; ++fn) {                                       \
          const int col = k0 + fn*16 + l16;                                    \
          _Pragma("unroll")                                                    \
          for (int r = 0; r < 4; ++r) {                                        \
            const int row = q0 + mf*16 + quad*4 + r;                           \
            if (col > row) sf[mf][fn][r] = -1e30f;                             \
          }                                                                    \
        }                                                                      \
    }                                                                          \
    /* fixed-max exp2: P = exp2(sf - SMAX); masked -> 0 */                     \
    _Pragma("unroll")                                                          \
    for (int mf = 0; mf < 2; ++mf)                                             \
      _Pragma("unroll")                                                        \
      for (int fn = 0; fn < 4; ++fn)                                           \
        _Pragma("unroll")                                                      \
        for (int r = 0; r < 4; ++r)                                            \
          sf[mf][fn][r] = EXP2F(sf[mf][fn][r] - SMAX);                         \
    _Pragma("unroll")                                                          \
    for (int mf = 0; mf < 2; ++mf)                                             \
      _Pragma("unroll")                                                        \
      for (int r = 0; r < 4; ++r)                                              \
        l_[mf][r] += (sf[mf][0][r] + sf[mf][1][r]) +                           \
                     (sf[mf][2][r] + sf[mf][3][r]);                            \
    /* P: C-layout -> LDS -> A-layout */                                       \
    _Pragma("unroll")                                                          \
    for (int mf = 0; mf < 2; ++mf)                                             \
      _Pragma("unroll")                                                        \
      for (int fn = 0; fn < 4; ++fn)                                           \
        _Pragma("unroll")                                                      \
        for (int r = 0; r < 4; ++r)                                            \
          Pw[(mf*16 + quad*4 + r)*88 + fn*16 + l16] = (__bf16)sf[mf][fn][r];   \
    bf16x8 pa[2][2];                                                           \
    _Pragma("unroll")                                                          \
    for (int mf = 0; mf < 2; ++mf)                                             \
      _Pragma("unroll")                                                        \
      for (int kq = 0; kq < 2; ++kq)                                           \
        pa[mf][kq] = *(const bf16x8*)&Pw[(mf*16 + l16)*88 + kq*32 + quad*8];   \
    /* O += P V (16 MFMAs) */                                                  \
    __builtin_amdgcn_s_setprio(1);                                             \
    _Pragma("unroll")                                                          \
    for (int mf = 0; mf < 2; ++mf)                                             \
      _Pragma("unroll")                                                        \
      for (int nd = 0; nd < 4; ++nd) {                                         \
        of[mf][nd] = MFMA16(pa[mf][0], vf[nd][0], of[mf][nd]);                 \
        of[mf][nd] = MFMA16(pa[mf][1], vf[nd][1], of[mf][nd]);                 \
      }                                                                        \
    __builtin_amdgcn_s_setprio(0);                                             \
  }

  for (int kt = 0; kt < ktiles; kt += 2) {
    TILE_STEP(kfA, kfB, kt);
    if (kt + 1 < ktiles) TILE_STEP(kfB, kfA, kt + 1);
  }
#undef TILE_STEP

  // ---- deferred l reduction (once), then normalize + store ----
#pragma unroll
  for (int d = 1; d < 16; d <<= 1)
#pragma unroll
    for (int mf = 0; mf < 2; ++mf)
#pragma unroll
      for (int r = 0; r < 4; ++r)
        l_[mf][r] += __shfl_xor(l_[mf][r], d);
#pragma unroll
  for (int mf = 0; mf < 2; ++mf)
#pragma unroll
    for (int r = 0; r < 4; ++r)
      l_[mf][r] = 1.0f / l_[mf][r];
#pragma unroll
  for (int mf = 0; mf < 2; ++mf)
#pragma unroll
    for (int nd = 0; nd < 4; ++nd) {
      const int dh = nd*16 + l16;
#pragma unroll
      for (int r = 0; r < 4; ++r) {
        const int q = q0 + mf*16 + quad*4 + r;
        attnb[((size_t)b*SEQ + q)*DIM + h*DH + dh] = (__bf16)(of[mf][nd][r] * l_[mf][r]);
      }
    }
}

// ---------------------------------------------------------------------------
extern "C" void kernel_launch(void* const* d_in, const int* in_sizes, int n_in,
                              void* d_out, int out_size, void* d_ws, size_t ws_size,
                              hipStream_t stream) {
  const float* x  = (const float*)d_in[0];
  // d_in[1] = causal mask, unused (causality computed analytically)
  const float* Wq = (const float*)d_in[2];
  const float* bq = (const float*)d_in[3];
  const float* Wk = (const float*)d_in[4];
  const float* bk = (const float*)d_in[5];
  const float* Wv = (const float*)d_in[6];
  const float* bv = (const float*)d_in[7];
  const float* Wo = (const float*)d_in[8];
  const float* bo = (const float*)d_in[9];
  float* out = (float*)d_out;

  // workspace carve-up (bf16 elements), total ~44 MB
  __bf16* xb    = (__bf16*)d_ws;
  __bf16* wq    = xb + (size_t)NTOK*DIM;
  __bf16* wk    = wq + DIM*DIM;
  __bf16* wv    = wk + DIM*DIM;
  __bf16* wo    = wv + DIM*DIM;
  __bf16* Qb    = wo + DIM*DIM;
  __bf16* Kb    = Qb + (size_t)NTOK*DIM;
  __bf16* Vt    = Kb + (size_t)NTOK*DIM;
  __bf16* attnb = Vt + (size_t)NTOK*DIM;

  // all converts in one launch (2560 blocks)
  cvt_all<<<2560, 256, 0, stream>>>(x, Wq, Wk, Wv, Wo, xb, wq, wk, wv, wo);

  // Q/K/V projections (coalesced LDS-retiled epilogue)
  gemm_qkv<<<dim3(NTOK/128, DIM/128, 3), 256, 0, stream>>>(
      xb, wq, wk, wv, bq, bk, bv, Qb, Kb, Vt);

  // flash attention (one-wave blocks, fixed-max softmax)
  flash_attn<<<2048, 64, 0, stream>>>(Qb, Kb, Vt, attnb);

  // output projection (64x128 tiles, 512 blocks)
  gemm_out<<<dim3(NTOK/64, DIM/128), 256, 0, stream>>>(attnb, wo, bo, out);
}